// Round 1
// baseline (1705.030 us; speedup 1.0000x reference)
//
#include <hip/hip_runtime.h>

// ---------------------------------------------------------------------------
// Spatial memory op, f32 baseline.
//   B=512, HW(centers)=225, C=VD=256, feat 15x15, decay 0.92
//   out = [ mem_out (512*512*225) | p (512*225*225) ]  (f32)
// Design notes:
//  - 1-wave (64-thread) blocks, per-thread 16x12 f32 register tile
//    -> 192 FMA per 7 b128 LDS reads: VALU-bound, not LDS-bound.
//  - m_in / m_out staged transposed-in-LDS with +4 words pad per 16 rows so
//    row-direction float4 reads are <=2-way bank conflicts (free on CDNA4).
//  - XCD swizzle: 5 column-tiles of one batch land on one XCD's L2.
//  - softmax held in registers; two small LDS reductions across the 15
//    row-thread-groups; p written straight to global.
// ---------------------------------------------------------------------------

constexpr int BB  = 512;
constexpr int CC  = 256;
constexpr int VD  = 256;
constexpr int HW  = 225;   // 15*15 centers
constexpr int MT  = 45;    // real columns per tile (225 = 5*45)
constexpr int MTP = 48;    // padded columns
constexpr int NMT = 5;
constexpr int CK  = 16;    // K-chunk for GEMM1 staging
constexpr float L2DECAY = -0.12029423371771177f; // log2(0.92)

constexpr size_t MEMOUT_PER_B = (size_t)(VD + 256) * HW;       // 115200
constexpr size_t P_BASE       = (size_t)BB * MEMOUT_PER_B;     // 58982400
constexpr size_t P_PER_B      = (size_t)HW * HW;               // 50625

__device__ __forceinline__ int swz_gt(int bid, int nblocks) {
    // nblocks % 8 == 0: bijective XCD swizzle (consecutive work chunks on one XCD)
    return (bid & 7) * (nblocks >> 3) + (bid >> 3);
}

// ---------------------------------------------------------------------------
// K1: scores + mask + softmax(over n) -> p
// grid 2560 = 512 batches * 5 col-tiles, block 64 threads
// thread map: tc = tid&3 (12 cols each, 48 padded), tr = tid>>2 (16 rows each,
// active tr<15 -> 240 padded rows over 225 real)
// ---------------------------------------------------------------------------
__global__ __launch_bounds__(64) void k1_scores_softmax(
    const float* __restrict__ m_in, const float* __restrict__ q_in,
    float* __restrict__ out)
{
    const int gt = swz_gt((int)blockIdx.x, BB * NMT);
    const int b  = gt / NMT;
    const int mt = gt % NMT;
    const int m0 = mt * MT;

    __shared__ float qs [CK][MTP];   // 3 KB
    __shared__ float mst[CK][300];   // 19.2 KB, transposed m_in chunk, padded rows
    __shared__ float red1[15][MTP];  // col partial max
    __shared__ float red2[15][MTP];  // col partial sum

    const int tid = threadIdx.x;
    const int tc  = tid & 3;
    const int tr  = tid >> 2;        // [0,16), compute-active < 15

    float acc[16][12];
    #pragma unroll
    for (int i = 0; i < 16; ++i)
        #pragma unroll
        for (int j = 0; j < 12; ++j) acc[i][j] = 0.f;

    const float* mi = m_in + (size_t)b * HW * CC;
    const float* qi = q_in + (size_t)b * CC * HW;

    for (int c0 = 0; c0 < CC; c0 += CK) {
        __syncthreads();
        // stage q chunk [CK][48], zero pad cols
        for (int f = tid; f < CK * MTP; f += 64) {
            int cl = f / MTP, m = f - cl * MTP;
            qs[cl][m] = (m < MT) ? qi[(size_t)(c0 + cl) * HW + m0 + m] : 0.f;
        }
        // stage m_in chunk transposed: mst[cl][phys(n)], phys = n + (n>>4)*4
        for (int f = tid; f < HW * CK; f += 64) {
            int n = f >> 4, cl = f & (CK - 1);
            mst[cl][n + ((n >> 4) << 2)] = mi[(size_t)n * CC + c0 + cl];
        }
        __syncthreads();
        if (tr < 15) {
            for (int cl = 0; cl < CK; ++cl) {
                // rows n = tr*16+i -> phys tr*20+i (contiguous 16)
                const float4 a0 = *(const float4*)&mst[cl][tr * 20 + 0];
                const float4 a1 = *(const float4*)&mst[cl][tr * 20 + 4];
                const float4 a2 = *(const float4*)&mst[cl][tr * 20 + 8];
                const float4 a3 = *(const float4*)&mst[cl][tr * 20 + 12];
                const float4 b0 = *(const float4*)&qs[cl][tc * 12 + 0];
                const float4 b1 = *(const float4*)&qs[cl][tc * 12 + 4];
                const float4 b2 = *(const float4*)&qs[cl][tc * 12 + 8];
                const float av[16] = {a0.x,a0.y,a0.z,a0.w, a1.x,a1.y,a1.z,a1.w,
                                      a2.x,a2.y,a2.z,a2.w, a3.x,a3.y,a3.z,a3.w};
                const float bv[12] = {b0.x,b0.y,b0.z,b0.w, b1.x,b1.y,b1.z,b1.w,
                                      b2.x,b2.y,b2.z,b2.w};
                #pragma unroll
                for (int i = 0; i < 16; ++i)
                    #pragma unroll
                    for (int j = 0; j < 12; ++j)
                        acc[i][j] = fmaf(av[i], bv[j], acc[i][j]);
            }
        }
    }

    // ---- scale + decay mask, then column softmax over n ----
    if (tr < 15) {
        #pragma unroll
        for (int i = 0; i < 16; ++i) {
            const int n = tr * 16 + i;
            #pragma unroll
            for (int j = 0; j < 12; ++j) {
                const int lm = tc * 12 + j;
                if (n >= HW) { acc[i][j] = -1e30f; }        // pad rows: excluded
                else if (lm < MT) {
                    const int mg = m0 + lm;
                    int dx = n / 15 - mg / 15;  dx = dx < 0 ? -dx : dx;
                    int dy = n % 15 - mg % 15;  dy = dy < 0 ? -dy : dy;
                    acc[i][j] = acc[i][j] * 0.0625f
                              * exp2f((float)(dx + dy) * L2DECAY);
                } else acc[i][j] = 0.f;                      // pad cols: benign
            }
        }
        #pragma unroll
        for (int j = 0; j < 12; ++j) {
            float mx = acc[0][j];
            #pragma unroll
            for (int i = 1; i < 16; ++i) mx = fmaxf(mx, acc[i][j]);
            red1[tr][tc * 12 + j] = mx;
        }
    }
    __syncthreads();
    float mxs[12], ps[12];
    if (tr < 15) {
        #pragma unroll
        for (int j = 0; j < 12; ++j) {
            float mx = red1[0][tc * 12 + j];
            #pragma unroll
            for (int t = 1; t < 15; ++t) mx = fmaxf(mx, red1[t][tc * 12 + j]);
            mxs[j] = mx; ps[j] = 0.f;
        }
        #pragma unroll
        for (int i = 0; i < 16; ++i)
            #pragma unroll
            for (int j = 0; j < 12; ++j) {
                const float e = expf(acc[i][j] - mxs[j]);  // -1e30 rows -> 0
                acc[i][j] = e;
                ps[j] += e;
            }
        #pragma unroll
        for (int j = 0; j < 12; ++j) red2[tr][tc * 12 + j] = ps[j];
    }
    __syncthreads();
    if (tr < 15) {
        float rinv[12];
        #pragma unroll
        for (int j = 0; j < 12; ++j) {
            float s = red2[0][tc * 12 + j];
            #pragma unroll
            for (int t = 1; t < 15; ++t) s += red2[t][tc * 12 + j];
            rinv[j] = 1.f / s;
        }
        float* pout = out + P_BASE + (size_t)b * P_PER_B;
        #pragma unroll
        for (int i = 0; i < 16; ++i) {
            const int n = tr * 16 + i;
            if (n < HW) {
                #pragma unroll
                for (int j = 0; j < 12; ++j) {
                    const int lm = tc * 12 + j;
                    if (lm < MT) pout[(size_t)n * HW + m0 + lm] = acc[i][j] * rinv[j];
                }
            }
        }
    }
}

// ---------------------------------------------------------------------------
// K2: mem[b,v,m] = sum_n m_out[b,n,v] * p[b,n,m]
// grid 2560 = 512 * 5 col-tiles, block 64; tv = tid>>2 (16 v-rows each, all
// 256 v covered exactly), tc = tid&3 (12 cols each). K chunks of 15 (225=15*15)
// ---------------------------------------------------------------------------
__global__ __launch_bounds__(64) void k2_mem(
    const float* __restrict__ m_out, const float* __restrict__ pbuf,
    float* __restrict__ out)
{
    const int gt = swz_gt((int)blockIdx.x, BB * NMT);
    const int b  = gt / NMT;
    const int mt = gt % NMT;
    const int m0 = mt * MT;

    __shared__ float As[15][320];   // 19.2 KB, m_out chunk, padded v
    __shared__ float Bs[15][MTP];   // 2.9 KB, p chunk

    const int tid = threadIdx.x;
    const int tc  = tid & 3;
    const int tv  = tid >> 2;       // [0,16), all active

    float acc[16][12];
    #pragma unroll
    for (int i = 0; i < 16; ++i)
        #pragma unroll
        for (int j = 0; j < 12; ++j) acc[i][j] = 0.f;

    const float* mo = m_out + (size_t)b * HW * VD;
    const float* pb = pbuf + P_BASE + (size_t)b * P_PER_B;

    for (int n0 = 0; n0 < HW; n0 += 15) {
        __syncthreads();
        for (int f = tid; f < 15 * VD; f += 64) {
            int nl = f >> 8, v = f & 255;
            As[nl][v + ((v >> 4) << 2)] = mo[(size_t)(n0 + nl) * VD + v];
        }
        for (int f = tid; f < 15 * MTP; f += 64) {
            int nl = f / MTP, m = f - nl * MTP;
            Bs[nl][m] = (m < MT) ? pb[(size_t)(n0 + nl) * HW + m0 + m] : 0.f;
        }
        __syncthreads();
        for (int nl = 0; nl < 15; ++nl) {
            const float4 a0 = *(const float4*)&As[nl][tv * 20 + 0];
            const float4 a1 = *(const float4*)&As[nl][tv * 20 + 4];
            const float4 a2 = *(const float4*)&As[nl][tv * 20 + 8];
            const float4 a3 = *(const float4*)&As[nl][tv * 20 + 12];
            const float4 b0 = *(const float4*)&Bs[nl][tc * 12 + 0];
            const float4 b1 = *(const float4*)&Bs[nl][tc * 12 + 4];
            const float4 b2 = *(const float4*)&Bs[nl][tc * 12 + 8];
            const float av[16] = {a0.x,a0.y,a0.z,a0.w, a1.x,a1.y,a1.z,a1.w,
                                  a2.x,a2.y,a2.z,a2.w, a3.x,a3.y,a3.z,a3.w};
            const float bv[12] = {b0.x,b0.y,b0.z,b0.w, b1.x,b1.y,b1.z,b1.w,
                                  b2.x,b2.y,b2.z,b2.w};
            #pragma unroll
            for (int i = 0; i < 16; ++i)
                #pragma unroll
                for (int j = 0; j < 12; ++j)
                    acc[i][j] = fmaf(av[i], bv[j], acc[i][j]);
        }
    }

    float* ob = out + (size_t)b * MEMOUT_PER_B;
    #pragma unroll
    for (int i = 0; i < 16; ++i) {
        const int v = tv * 16 + i;
        #pragma unroll
        for (int j = 0; j < 12; ++j) {
            const int lm = tc * 12 + j;
            if (lm < MT) ob[(size_t)v * HW + m0 + lm] = acc[i][j];
        }
    }
}

// ---------------------------------------------------------------------------
// K3: copy q_out into second channel half of mem_out (float4, fully coalesced)
// 512 * 57600 floats = 512 * 14400 float4
// ---------------------------------------------------------------------------
__global__ __launch_bounds__(256) void k3_copy(
    const float4* __restrict__ q_out, float4* __restrict__ out)
{
    const size_t g = (size_t)blockIdx.x * 256 + threadIdx.x;  // < 512*14400
    const size_t b = g / 14400;
    const size_t r = g - b * 14400;
    out[b * 28800 + 14400 + r] = q_out[b * 14400 + r];
}

extern "C" void kernel_launch(void* const* d_in, const int* in_sizes, int n_in,
                              void* d_out, int out_size, void* d_ws, size_t ws_size,
                              hipStream_t stream) {
    const float* m_in  = (const float*)d_in[0];
    const float* m_out = (const float*)d_in[1];
    const float* q_in  = (const float*)d_in[2];
    const float* q_out = (const float*)d_in[3];
    float* out = (float*)d_out;

    k1_scores_softmax<<<BB * NMT, 64, 0, stream>>>(m_in, q_in, out);
    k2_mem<<<BB * NMT, 64, 0, stream>>>(m_out, out, out);
    k3_copy<<<(BB * 14400) / 256, 256, 0, stream>>>((const float4*)q_out, (float4*)out);
}

// Round 2
// 1670.467 us; speedup vs baseline: 1.0207x; 1.0207x over previous
//
#include <hip/hip_runtime.h>

// ---------------------------------------------------------------------------
// Spatial memory op — split-bf16 MFMA version.
//   B=512, HW=225, C=VD=256.  out = [ mem_out (512ch) | p ]
//   k1: S = m_in·q_in /16 * decaymask; p = softmax_n(S)  (MFMA + in-reg softmax)
//   k2: mem = m_out^T · p                                (MFMA)
//   k3: copy q_out into channels 256..511
// Precision: f32 operands split into bf16 hi+lo; 3 MFMAs per product
// (hi*hi + hi*lo + lo*hi) ≈ f32 accuracy (~2^-18 rel per term).
// Layout facts used (cdna_hip_programming.md §3, m89/m92-verified):
//   A/B frag: row|col = lane&15, k = (lane>>4)*8 + e (8 contiguous bf16 = b128)
//   C/D:      col = lane&15, row = (lane>>4)*4 + reg
// ---------------------------------------------------------------------------

typedef float  f32x4 __attribute__((ext_vector_type(4)));
typedef short  s16x8 __attribute__((ext_vector_type(8)));
typedef unsigned int   u32;
typedef unsigned short u16;

constexpr int   BB = 512, HW = 225, CC = 256;
constexpr float L2DECAY = -0.12029423371771177f;   // log2(0.92)
constexpr float L2E     = 1.4426950408889634f;
constexpr size_t MEMOUT_PER_B = (size_t)512 * HW;          // 115200
constexpr size_t P_BASE       = (size_t)BB * MEMOUT_PER_B; // 58982400
constexpr size_t P_PER_B      = (size_t)HW * HW;           // 50625
constexpr int SR = 40;  // LDS row stride in bf16 (80 B = 5×16 B, even bank spread)

__device__ __forceinline__ int swz(int bid, int nb) {  // bijective XCD swizzle
    return (bid & 7) * (nb >> 3) + (bid >> 3);
}
__device__ __forceinline__ u16 f2bf(float x) {
    u32 u = __builtin_bit_cast(u32, x);
    u += 0x7fff + ((u >> 16) & 1);
    return (u16)(u >> 16);
}
__device__ __forceinline__ void split2(float x, u16& h, u16& l) {
    h = f2bf(x);
    float hf = __builtin_bit_cast(float, (u32)h << 16);
    l = f2bf(x - hf);
}

// ---------------------------------------------------------------------------
// k1: scores + mask + softmax over n -> p   (grid 1024 = 512 b × 2 col-halves)
// block 512 thr = 8 waves (4 row-waves × 2 col-waves), wave tile 64×64
// ---------------------------------------------------------------------------
__global__ __launch_bounds__(512, 4) void k1_mfma(
    const float* __restrict__ m_in, const float* __restrict__ q_in,
    float* __restrict__ out)
{
    __shared__ u16 Ah[256 * SR], Al[256 * SR];   // m_in rows (n), k-contig
    __shared__ u16 Bh[128 * SR], Bl[128 * SR];   // q^T rows (m), k-contig
    __shared__ float red[4][128];

    const int bid  = swz((int)blockIdx.x, 1024);
    const int b    = bid >> 1, half = bid & 1;
    const int mB0  = half * 128;
    const int tid  = threadIdx.x, lane = tid & 63, wid = tid >> 6;
    const int wr   = wid & 3, wc = wid >> 2;
    const int l15  = lane & 15, lg = lane >> 4;

    const float* mi = m_in + (size_t)b * HW * CC;
    const float* qi = q_in + (size_t)b * CC * HW;

    f32x4 acc[4][4];
    #pragma unroll
    for (int i = 0; i < 4; ++i)
        #pragma unroll
        for (int j = 0; j < 4; ++j) acc[i][j] = {0.f, 0.f, 0.f, 0.f};

    int aoff[4], boff[4];
    #pragma unroll
    for (int f = 0; f < 4; ++f) {
        aoff[f] = (wr * 64 + f * 16 + l15) * SR + lg * 8;
        boff[f] = (wc * 64 + f * 16 + l15) * SR + lg * 8;
    }

    for (int c0 = 0; c0 < CC; c0 += 32) {
        __syncthreads();
        // stage m_in chunk [256 n][32 k], zero pad rows
        #pragma unroll
        for (int it = 0; it < 16; ++it) {
            int f = it * 512 + tid, n = f >> 5, cl = f & 31;
            float x = (n < HW) ? mi[n * CC + c0 + cl] : 0.f;
            u16 h, l; split2(x, h, l);
            Ah[n * SR + cl] = h; Al[n * SR + cl] = l;
        }
        // stage q^T chunk [128 m][32 k], zero pad cols
        #pragma unroll
        for (int it = 0; it < 8; ++it) {
            int f = it * 512 + tid, ml = f & 127, cl = f >> 7;
            int m = mB0 + ml;
            float x = (m < HW) ? qi[(c0 + cl) * HW + m] : 0.f;
            u16 h, l; split2(x, h, l);
            Bh[ml * SR + cl] = h; Bl[ml * SR + cl] = l;
        }
        __syncthreads();
        s16x8 ah[4], al[4];
        #pragma unroll
        for (int fr = 0; fr < 4; ++fr) {
            ah[fr] = *(const s16x8*)&Ah[aoff[fr]];
            al[fr] = *(const s16x8*)&Al[aoff[fr]];
        }
        #pragma unroll
        for (int fc = 0; fc < 4; ++fc) {
            s16x8 bh = *(const s16x8*)&Bh[boff[fc]];
            s16x8 bl = *(const s16x8*)&Bl[boff[fc]];
            #pragma unroll
            for (int fr = 0; fr < 4; ++fr) {
                acc[fr][fc] = __builtin_amdgcn_mfma_f32_16x16x32_bf16(al[fr], bh, acc[fr][fc], 0, 0, 0);
                acc[fr][fc] = __builtin_amdgcn_mfma_f32_16x16x32_bf16(ah[fr], bl, acc[fr][fc], 0, 0, 0);
                acc[fr][fc] = __builtin_amdgcn_mfma_f32_16x16x32_bf16(ah[fr], bh, acc[fr][fc], 0, 0, 0);
            }
        }
    }

    // ---- scale + decay mask; column softmax over n (rows) ----
    float mx[4];
    #pragma unroll
    for (int fc = 0; fc < 4; ++fc) {
        const int m   = mB0 + wc * 64 + fc * 16 + l15;   // may be >=225 (pad col, benign)
        const int mgx = m / 15, mgy = m % 15;
        float cmx = -3.0e38f;
        #pragma unroll
        for (int fr = 0; fr < 4; ++fr)
            #pragma unroll
            for (int r = 0; r < 4; ++r) {
                const int n = wr * 64 + fr * 16 + lg * 4 + r;
                float s;
                if (n < HW) {
                    int dx = n / 15 - mgx; dx = dx < 0 ? -dx : dx;
                    int dy = n % 15 - mgy; dy = dy < 0 ? -dy : dy;
                    s = acc[fr][fc][r] * 0.0625f * exp2f((float)(dx + dy) * L2DECAY);
                } else s = -3.0e38f;
                acc[fr][fc][r] = s;
                cmx = fmaxf(cmx, s);
            }
        cmx = fmaxf(cmx, __shfl_xor(cmx, 16));
        cmx = fmaxf(cmx, __shfl_xor(cmx, 32));
        mx[fc] = cmx;
    }
    if (lane < 16) {
        #pragma unroll
        for (int fc = 0; fc < 4; ++fc) red[wr][wc * 64 + fc * 16 + lane] = mx[fc];
    }
    __syncthreads();
    #pragma unroll
    for (int fc = 0; fc < 4; ++fc) {
        const int col = wc * 64 + fc * 16 + l15;
        mx[fc] = fmaxf(fmaxf(red[0][col], red[1][col]), fmaxf(red[2][col], red[3][col]));
    }
    __syncthreads();   // before reusing red for sums
    float sm[4];
    #pragma unroll
    for (int fc = 0; fc < 4; ++fc) {
        float s = 0.f;
        #pragma unroll
        for (int fr = 0; fr < 4; ++fr)
            #pragma unroll
            for (int r = 0; r < 4; ++r) {
                float e = exp2f((acc[fr][fc][r] - mx[fc]) * L2E);
                acc[fr][fc][r] = e;
                s += e;
            }
        s += __shfl_xor(s, 16);
        s += __shfl_xor(s, 32);
        sm[fc] = s;
    }
    if (lane < 16) {
        #pragma unroll
        for (int fc = 0; fc < 4; ++fc) red[wr][wc * 64 + fc * 16 + lane] = sm[fc];
    }
    __syncthreads();
    float* pout = out + P_BASE + (size_t)b * P_PER_B;
    #pragma unroll
    for (int fc = 0; fc < 4; ++fc) {
        const int col = wc * 64 + fc * 16 + l15;
        const float inv = 1.f / (red[0][col] + red[1][col] + red[2][col] + red[3][col]);
        const int m = mB0 + wc * 64 + fc * 16 + l15;
        if (m < HW) {
            #pragma unroll
            for (int fr = 0; fr < 4; ++fr)
                #pragma unroll
                for (int r = 0; r < 4; ++r) {
                    const int n = wr * 64 + fr * 16 + lg * 4 + r;
                    if (n < HW) pout[(size_t)n * HW + m] = acc[fr][fc][r] * inv;
                }
        }
    }
}

// ---------------------------------------------------------------------------
// k2: mem[v,m] = sum_n m_out[n,v] * p[n,m]   (grid 1024 = 512 b × 2 halves)
// A2 = m_out^T [v][n-chunk], B2 = p^T [m][n-chunk]; wave tile 64×64
// ---------------------------------------------------------------------------
__global__ __launch_bounds__(512, 4) void k2_mfma(
    const float* __restrict__ m_out, float* __restrict__ out)
{
    __shared__ u16 Ah[256 * SR], Al[256 * SR];   // m_out^T rows (v), k=n contig
    __shared__ u16 Bh[128 * SR], Bl[128 * SR];   // p^T rows (m), k=n contig

    const int bid  = swz((int)blockIdx.x, 1024);
    const int b    = bid >> 1, half = bid & 1;
    const int mB0  = half * 128;
    const int tid  = threadIdx.x, lane = tid & 63, wid = tid >> 6;
    const int vr   = wid & 3, wc = wid >> 2;
    const int l15  = lane & 15, lg = lane >> 4;

    const float* mo = m_out + (size_t)b * HW * CC;
    const float* pb = out + P_BASE + (size_t)b * P_PER_B;

    f32x4 acc[4][4];
    #pragma unroll
    for (int i = 0; i < 4; ++i)
        #pragma unroll
        for (int j = 0; j < 4; ++j) acc[i][j] = {0.f, 0.f, 0.f, 0.f};

    int aoff[4], boff[4];
    #pragma unroll
    for (int f = 0; f < 4; ++f) {
        aoff[f] = (vr * 64 + f * 16 + l15) * SR + lg * 8;
        boff[f] = (wc * 64 + f * 16 + l15) * SR + lg * 8;
    }

    for (int n0 = 0; n0 < 256; n0 += 32) {
        __syncthreads();
        // stage m_out^T chunk [256 v][32 n] (transpose), zero pad n
        #pragma unroll
        for (int it = 0; it < 16; ++it) {
            int f = it * 512 + tid, v = f & 255, nl = f >> 8;
            int n = n0 + nl;
            float x = (n < HW) ? mo[n * CC + v] : 0.f;
            u16 h, l; split2(x, h, l);
            Ah[v * SR + nl] = h; Al[v * SR + nl] = l;
        }
        // stage p^T chunk [128 m][32 n] (transpose), zero pads
        #pragma unroll
        for (int it = 0; it < 8; ++it) {
            int f = it * 512 + tid, ml = f & 127, nl = f >> 7;
            int n = n0 + nl, m = mB0 + ml;
            float x = (n < HW && m < HW) ? pb[(size_t)n * HW + m] : 0.f;
            u16 h, l; split2(x, h, l);
            Bh[ml * SR + nl] = h; Bl[ml * SR + nl] = l;
        }
        __syncthreads();
        s16x8 ah[4], al[4];
        #pragma unroll
        for (int fr = 0; fr < 4; ++fr) {
            ah[fr] = *(const s16x8*)&Ah[aoff[fr]];
            al[fr] = *(const s16x8*)&Al[aoff[fr]];
        }
        #pragma unroll
        for (int fc = 0; fc < 4; ++fc) {
            s16x8 bh = *(const s16x8*)&Bh[boff[fc]];
            s16x8 bl = *(const s16x8*)&Bl[boff[fc]];
            #pragma unroll
            for (int fr = 0; fr < 4; ++fr) {
                acc[fr][fc] = __builtin_amdgcn_mfma_f32_16x16x32_bf16(al[fr], bh, acc[fr][fc], 0, 0, 0);
                acc[fr][fc] = __builtin_amdgcn_mfma_f32_16x16x32_bf16(ah[fr], bl, acc[fr][fc], 0, 0, 0);
                acc[fr][fc] = __builtin_amdgcn_mfma_f32_16x16x32_bf16(ah[fr], bh, acc[fr][fc], 0, 0, 0);
            }
        }
    }

    float* ob = out + (size_t)b * MEMOUT_PER_B;
    #pragma unroll
    for (int fc = 0; fc < 4; ++fc) {
        const int m = mB0 + wc * 64 + fc * 16 + l15;
        if (m < HW) {
            #pragma unroll
            for (int fr = 0; fr < 4; ++fr)
                #pragma unroll
                for (int r = 0; r < 4; ++r) {
                    const int v = vr * 64 + fr * 16 + lg * 4 + r;
                    ob[(size_t)v * HW + m] = acc[fr][fc][r];
                }
        }
    }
}

// ---------------------------------------------------------------------------
// k3: copy q_out into second channel half of mem_out (float4 coalesced)
// ---------------------------------------------------------------------------
__global__ __launch_bounds__(256) void k3_copy(
    const float4* __restrict__ q_out, float4* __restrict__ out)
{
    const size_t g = (size_t)blockIdx.x * 256 + threadIdx.x;  // < 512*14400
    const size_t b = g / 14400;
    const size_t r = g - b * 14400;
    out[b * 28800 + 14400 + r] = q_out[b * 14400 + r];
}

extern "C" void kernel_launch(void* const* d_in, const int* in_sizes, int n_in,
                              void* d_out, int out_size, void* d_ws, size_t ws_size,
                              hipStream_t stream) {
    const float* m_in  = (const float*)d_in[0];
    const float* m_out = (const float*)d_in[1];
    const float* q_in  = (const float*)d_in[2];
    const float* q_out = (const float*)d_in[3];
    float* out = (float*)d_out;

    k1_mfma<<<1024, 512, 0, stream>>>(m_in, q_in, out);
    k2_mfma<<<1024, 512, 0, stream>>>(m_out, out);
    k3_copy<<<(512 * 14400) / 256, 256, 0, stream>>>((const float4*)q_out, (float4*)out);
}

// Round 9
// 745.040 us; speedup vs baseline: 2.2885x; 2.2421x over previous
//
#include <hip/hip_runtime.h>

// ---------------------------------------------------------------------------
// Spatial memory — pure-bf16 MFMA version (single MFMA per product).
//   Evidence: rounds 1 (f32-exact) and 2 (split-bf16) both absmax=2^-9 ->
//   reference itself is bf16-matmul quality; f32 accumulate in MFMA matches.
//   k1: S = (m_in·q_in)/16 * mask; p = softmax_n(S). block 256n x 128m, 8 waves.
//   k2: mem = m_out^T · p. block 256v x 128m, 8 waves.
//   k3: copy q_out -> channels 256..511.
// Registers: acc 64 + frags ~20 + addr -> ~105, fits 128 cap (2 blocks/CU), no spill.
// LDS 57.3 KB: A[256][72] + B[128][72] bf16 (SR=72: 144 B rows, 16B-aligned frags,
// conflict-free b128 reads: start bank = 4*((l15+lg)&7)).
// ---------------------------------------------------------------------------

typedef float  f32x4 __attribute__((ext_vector_type(4)));
typedef short  s16x8 __attribute__((ext_vector_type(8)));
typedef unsigned short u16;
typedef u16    u16x4 __attribute__((ext_vector_type(4)));
typedef unsigned int   u32;

constexpr int   BB = 512, HW = 225, CC = 256;
constexpr float L2DECAY = -0.12029423371771177f;   // log2(0.92)
constexpr float L2E     = 1.4426950408889634f;
constexpr size_t MEMOUT_PER_B = (size_t)512 * HW;          // 115200
constexpr size_t P_BASE       = (size_t)BB * MEMOUT_PER_B; // 58982400
constexpr size_t P_PER_B      = (size_t)HW * HW;           // 50625
constexpr int SR = 72;   // LDS row stride in bf16 (144 B = 9*16 B)

__device__ __forceinline__ int swz(int bid, int nb) {  // bijective XCD swizzle
    return (bid & 7) * (nb >> 3) + (bid >> 3);
}
__device__ __forceinline__ u16 f2bf(float x) {   // RNE, matches jax/bf16 cast
    u32 u = __builtin_bit_cast(u32, x);
    u += 0x7fff + ((u >> 16) & 1);
    return (u16)(u >> 16);
}

// ---------------------------------------------------------------------------
// k1: scores + mask + softmax over n -> p.  grid 1024 = 512 b x 2 halves,
// block 512 thr = 8 waves (4 row x 2 col), wave tile 64x64, K-chunk 64.
// ---------------------------------------------------------------------------
__global__ __launch_bounds__(512, 4) void k1_mfma(
    const float* __restrict__ m_in, const float* __restrict__ q_in,
    float* __restrict__ out)
{
    __shared__ u16 As[256 * SR];     // m_in rows (n), k-contig       36.9 KB
    __shared__ u16 Bs[128 * SR];     // q^T rows (m), k-contig        18.4 KB
    __shared__ float red[4][128];    //                                2.0 KB

    const int bid  = swz((int)blockIdx.x, 1024);
    const int b    = bid >> 1, half = bid & 1;
    const int mB0  = half * 128;
    const int tid  = threadIdx.x, lane = tid & 63, wid = tid >> 6;
    const int wr   = wid & 3, wc = wid >> 2;
    const int l15  = lane & 15, lg = lane >> 4;

    const float* mi = m_in + (size_t)b * HW * CC;
    const float* qi = q_in + (size_t)b * CC * HW;

    f32x4 acc[4][4];
    #pragma unroll
    for (int i = 0; i < 4; ++i)
        #pragma unroll
        for (int j = 0; j < 4; ++j) acc[i][j] = {0.f, 0.f, 0.f, 0.f};

    const int abase = (wr * 64 + l15) * SR + lg * 8;
    const int bbase = (wc * 64 + l15) * SR + lg * 8;

    for (int c0 = 0; c0 < CC; c0 += 64) {
        __syncthreads();
        // A stage: [256 n][64 k] as float4 row loads (coalesced, 16B-aligned)
        #pragma unroll
        for (int it = 0; it < 8; ++it) {
            const int f = it * 512 + tid, n = f >> 4, k4 = f & 15;
            float4 x = {0.f, 0.f, 0.f, 0.f};
            if (n < HW) x = *(const float4*)(mi + (size_t)n * CC + c0 + k4 * 4);
            u16x4 h = { f2bf(x.x), f2bf(x.y), f2bf(x.z), f2bf(x.w) };
            *(u16x4*)&As[n * SR + k4 * 4] = h;
        }
        // B stage (q transpose): dest (m, k-quad); 4 coalesced scalar streams
        #pragma unroll
        for (int it = 0; it < 4; ++it) {
            const int f = it * 512 + tid, ml = f & 127, c4 = f >> 7;
            const int m = mB0 + ml, c = c0 + c4 * 4;
            float x0 = 0.f, x1 = 0.f, x2 = 0.f, x3 = 0.f;
            if (m < HW) {
                x0 = qi[(size_t)(c + 0) * HW + m];
                x1 = qi[(size_t)(c + 1) * HW + m];
                x2 = qi[(size_t)(c + 2) * HW + m];
                x3 = qi[(size_t)(c + 3) * HW + m];
            }
            u16x4 h = { f2bf(x0), f2bf(x1), f2bf(x2), f2bf(x3) };
            *(u16x4*)&Bs[ml * SR + c4 * 4] = h;
        }
        __syncthreads();
        #pragma unroll
        for (int ks = 0; ks < 2; ++ks) {
            s16x8 a[4];
            #pragma unroll
            for (int fr = 0; fr < 4; ++fr)
                a[fr] = *(const s16x8*)&As[abase + fr * 16 * SR + ks * 32];
            #pragma unroll
            for (int fc = 0; fc < 4; ++fc) {
                const s16x8 bq = *(const s16x8*)&Bs[bbase + fc * 16 * SR + ks * 32];
                #pragma unroll
                for (int fr = 0; fr < 4; ++fr)
                    acc[fr][fc] = __builtin_amdgcn_mfma_f32_16x16x32_bf16(
                        a[fr], bq, acc[fr][fc], 0, 0, 0);
            }
        }
    }

    // ---- scale + decay mask; column softmax over n ----
    float mx[4];
    #pragma unroll
    for (int fc = 0; fc < 4; ++fc) {
        const int m   = mB0 + wc * 64 + fc * 16 + l15;   // >=225 pad col: benign
        const int mgx = m / 15, mgy = m % 15;
        float cmx = -3.0e38f;
        #pragma unroll
        for (int fr = 0; fr < 4; ++fr)
            #pragma unroll
            for (int r = 0; r < 4; ++r) {
                const int n = wr * 64 + fr * 16 + lg * 4 + r;
                float s;
                if (n < HW) {
                    int dx = n / 15 - mgx; dx = dx < 0 ? -dx : dx;
                    int dy = n % 15 - mgy; dy = dy < 0 ? -dy : dy;
                    s = acc[fr][fc][r] * 0.0625f * exp2f((float)(dx + dy) * L2DECAY);
                } else s = -3.0e38f;
                acc[fr][fc][r] = s;
                cmx = fmaxf(cmx, s);
            }
        cmx = fmaxf(cmx, __shfl_xor(cmx, 16));
        cmx = fmaxf(cmx, __shfl_xor(cmx, 32));
        mx[fc] = cmx;
    }
    if (lane < 16) {
        #pragma unroll
        for (int fc = 0; fc < 4; ++fc) red[wr][wc * 64 + fc * 16 + lane] = mx[fc];
    }
    __syncthreads();
    #pragma unroll
    for (int fc = 0; fc < 4; ++fc) {
        const int col = wc * 64 + fc * 16 + l15;
        mx[fc] = fmaxf(fmaxf(red[0][col], red[1][col]), fmaxf(red[2][col], red[3][col]));
    }
    __syncthreads();   // before reusing red for sums
    float sm[4];
    #pragma unroll
    for (int fc = 0; fc < 4; ++fc) {
        float s = 0.f;
        #pragma unroll
        for (int fr = 0; fr < 4; ++fr)
            #pragma unroll
            for (int r = 0; r < 4; ++r) {
                const float e = exp2f((acc[fr][fc][r] - mx[fc]) * L2E);
                acc[fr][fc][r] = e;
                s += e;
            }
        s += __shfl_xor(s, 16);
        s += __shfl_xor(s, 32);
        sm[fc] = s;
    }
    if (lane < 16) {
        #pragma unroll
        for (int fc = 0; fc < 4; ++fc) red[wr][wc * 64 + fc * 16 + lane] = sm[fc];
    }
    __syncthreads();
    float* pout = out + P_BASE + (size_t)b * P_PER_B;
    #pragma unroll
    for (int fc = 0; fc < 4; ++fc) {
        const int col = wc * 64 + fc * 16 + l15;
        const float inv = 1.f / (red[0][col] + red[1][col] + red[2][col] + red[3][col]);
        const int m = mB0 + wc * 64 + fc * 16 + l15;
        if (m < HW) {
            #pragma unroll
            for (int fr = 0; fr < 4; ++fr)
                #pragma unroll
                for (int r = 0; r < 4; ++r) {
                    const int n = wr * 64 + fr * 16 + lg * 4 + r;
                    if (n < HW) pout[(size_t)n * HW + m] = acc[fr][fc][r] * inv;
                }
        }
    }
}

// ---------------------------------------------------------------------------
// k2: mem[v,m] = sum_n m_out[n,v] * p[n,m].  grid 1024 = 512 b x 2 halves.
// ---------------------------------------------------------------------------
__global__ __launch_bounds__(512, 4) void k2_mfma(
    const float* __restrict__ m_out, float* __restrict__ out)
{
    __shared__ u16 As[256 * SR];     // m_out^T rows (v), k=n contig
    __shared__ u16 Bs[128 * SR];     // p^T rows (m), k=n contig

    const int bid  = swz((int)blockIdx.x, 1024);
    const int b    = bid >> 1, half = bid & 1;
    const int mB0  = half * 128;
    const int tid  = threadIdx.x, lane = tid & 63, wid = tid >> 6;
    const int vr   = wid & 3, wc = wid >> 2;
    const int l15  = lane & 15, lg = lane >> 4;

    const float* mo = m_out + (size_t)b * HW * CC;
    const float* pb = out + P_BASE + (size_t)b * P_PER_B;

    f32x4 acc[4][4];
    #pragma unroll
    for (int i = 0; i < 4; ++i)
        #pragma unroll
        for (int j = 0; j < 4; ++j) acc[i][j] = {0.f, 0.f, 0.f, 0.f};

    const int abase = (vr * 64 + l15) * SR + lg * 8;
    const int bbase = (wc * 64 + l15) * SR + lg * 8;

    for (int n0 = 0; n0 < 256; n0 += 64) {
        __syncthreads();
        // A stage (m_out transpose): dest (v, n-quad); coalesced along v
        #pragma unroll
        for (int it = 0; it < 8; ++it) {
            const int f = it * 512 + tid, v = f & 255, n4 = f >> 8;
            const int n = n0 + n4 * 4;
            const float x0 = (n + 0 < HW) ? mo[(size_t)(n + 0) * CC + v] : 0.f;
            const float x1 = (n + 1 < HW) ? mo[(size_t)(n + 1) * CC + v] : 0.f;
            const float x2 = (n + 2 < HW) ? mo[(size_t)(n + 2) * CC + v] : 0.f;
            const float x3 = (n + 3 < HW) ? mo[(size_t)(n + 3) * CC + v] : 0.f;
            u16x4 h = { f2bf(x0), f2bf(x1), f2bf(x2), f2bf(x3) };
            *(u16x4*)&As[v * SR + n4 * 4] = h;
        }
        // B stage (p transpose): dest (m, n-quad); coalesced along m
        #pragma unroll
        for (int it = 0; it < 4; ++it) {
            const int f = it * 512 + tid, ml = f & 127, n4 = f >> 7;
            const int m = mB0 + ml, n = n0 + n4 * 4;
            float x0 = 0.f, x1 = 0.f, x2 = 0.f, x3 = 0.f;
            if (m < HW) {
                if (n + 0 < HW) x0 = pb[(size_t)(n + 0) * HW + m];
                if (n + 1 < HW) x1 = pb[(size_t)(n + 1) * HW + m];
                if (n + 2 < HW) x2 = pb[(size_t)(n + 2) * HW + m];
                if (n + 3 < HW) x3 = pb[(size_t)(n + 3) * HW + m];
            }
            u16x4 h = { f2bf(x0), f2bf(x1), f2bf(x2), f2bf(x3) };
            *(u16x4*)&Bs[ml * SR + n4 * 4] = h;
        }
        __syncthreads();
        #pragma unroll
        for (int ks = 0; ks < 2; ++ks) {
            s16x8 a[4];
            #pragma unroll
            for (int fr = 0; fr < 4; ++fr)
                a[fr] = *(const s16x8*)&As[abase + fr * 16 * SR + ks * 32];
            #pragma unroll
            for (int fc = 0; fc < 4; ++fc) {
                const s16x8 bq = *(const s16x8*)&Bs[bbase + fc * 16 * SR + ks * 32];
                #pragma unroll
                for (int fr = 0; fr < 4; ++fr)
                    acc[fr][fc] = __builtin_amdgcn_mfma_f32_16x16x32_bf16(
                        a[fr], bq, acc[fr][fc], 0, 0, 0);
            }
        }
    }

    float* ob = out + (size_t)b * MEMOUT_PER_B;
    #pragma unroll
    for (int fc = 0; fc < 4; ++fc) {
        const int m = mB0 + wc * 64 + fc * 16 + l15;
        if (m < HW) {
            #pragma unroll
            for (int fr = 0; fr < 4; ++fr)
                #pragma unroll
                for (int r = 0; r < 4; ++r) {
                    const int v = vr * 64 + fr * 16 + lg * 4 + r;
                    ob[(size_t)v * HW + m] = acc[fr][fc][r];
                }
        }
    }
}

// ---------------------------------------------------------------------------
// k3: copy q_out into second channel half of mem_out (float4 coalesced)
// ---------------------------------------------------------------------------
__global__ __launch_bounds__(256) void k3_copy(
    const float4* __restrict__ q_out, float4* __restrict__ out)
{
    const size_t g = (size_t)blockIdx.x * 256 + threadIdx.x;  // < 512*14400
    const size_t b = g / 14400;
    const size_t r = g - b * 14400;
    out[b * 28800 + 14400 + r] = q_out[b * 14400 + r];
}

extern "C" void kernel_launch(void* const* d_in, const int* in_sizes, int n_in,
                              void* d_out, int out_size, void* d_ws, size_t ws_size,
                              hipStream_t stream) {
    const float* m_in  = (const float*)d_in[0];
    const float* m_out = (const float*)d_in[1];
    const float* q_in  = (const float*)d_in[2];
    const float* q_out = (const float*)d_in[3];
    float* out = (float*)d_out;

    k1_mfma<<<1024, 512, 0, stream>>>(m_in, q_in, out);
    k2_mfma<<<1024, 512, 0, stream>>>(m_out, out);
    k3_copy<<<(512 * 14400) / 256, 256, 0, stream>>>((const float4*)q_out, (float4*)out);
}

// Round 11
// 717.705 us; speedup vs baseline: 2.3757x; 1.0381x over previous
//
#include <hip/hip_runtime.h>

// ---------------------------------------------------------------------------
// Spatial memory — bf16 MFMA, v2: XCD-paired halves + double-buffered K-loop.
//   Evidence r9: kernels each <=216us (below fill dispatches), total 745us,
//   absmax 2^-8 passes -> bf16 matmul quality confirmed sufficient.
//   Changes vs r3..r8 kernel:
//   1) XCD swizzle now keeps BOTH m-halves of a batch on the SAME XCD
//      (they share m_in / m_out reads -> second read becomes an L2 hit).
//   2) K-chunk 64->32, LDS double-buffered (2x(256+128)x40 bf16 = 61.4KB,
//      still 2 blocks/CU), ONE barrier per iter; next-tile global loads
//      issued into registers BEFORE the MFMAs (T14 async-stage split).
//   SR=40 (80B rows, 16B-aligned): frag-read classes balanced (conflict-free),
//   A-stage writes conflict-free (10n+k4 mod 16 bijective).
// ---------------------------------------------------------------------------

typedef float  f32x4 __attribute__((ext_vector_type(4)));
typedef short  s16x8 __attribute__((ext_vector_type(8)));
typedef unsigned short u16;
typedef u16    u16x4 __attribute__((ext_vector_type(4)));
typedef unsigned int   u32;

constexpr int   BB = 512, HW = 225, CC = 256;
constexpr float L2DECAY = -0.12029423371771177f;   // log2(0.92)
constexpr float L2E     = 1.4426950408889634f;
constexpr size_t MEMOUT_PER_B = (size_t)512 * HW;          // 115200
constexpr size_t P_BASE       = (size_t)BB * MEMOUT_PER_B; // 58982400
constexpr size_t P_PER_B      = (size_t)HW * HW;           // 50625
constexpr int SR = 40;   // LDS row stride in u16 (80 B = 5*16 B)
constexpr int KC = 32;   // K-chunk

__device__ __forceinline__ u16 f2bf(float x) {   // RNE, matches jax/bf16 cast
    u32 u = __builtin_bit_cast(u32, x);
    u += 0x7fff + ((u >> 16) & 1);
    return (u16)(u >> 16);
}

// XCD-pair decode: both halves of batch b land on the same XCD.
__device__ __forceinline__ void decode_bid(int bid, int& b, int& half) {
    const int xcd = bid & 7, j = bid >> 3;     // 128 j's per XCD
    half = j & 1;
    b    = xcd * 64 + (j >> 1);                // batches 64x+0..63 on XCD x
}

// ---------------------------------------------------------------------------
// k1: scores + mask + softmax over n -> p.  grid 1024 = 512 b x 2 halves,
// block 512 thr = 8 waves (4 row x 2 col), wave tile 64x64, dbuf K=32.
// ---------------------------------------------------------------------------
__global__ __launch_bounds__(512, 2) void k1_mfma(
    const float* __restrict__ m_in, const float* __restrict__ q_in,
    float* __restrict__ out)
{
    __shared__ u16 As[2][256 * SR];   // m_in rows (n), k-contig   2x20.0 KB
    __shared__ u16 Bs[2][128 * SR];   // q^T rows (m), k-contig    2x10.0 KB
    __shared__ float red[4][128];     //                             2.0 KB

    int b, half;  decode_bid((int)blockIdx.x, b, half);
    const int mB0  = half * 128;
    const int tid  = threadIdx.x, lane = tid & 63, wid = tid >> 6;
    const int wr   = wid & 3, wc = wid >> 2;
    const int l15  = lane & 15, lg = lane >> 4;

    const float* mi = m_in + (size_t)b * HW * CC;
    const float* qi = q_in + (size_t)b * CC * HW;

    f32x4 acc[4][4];
    #pragma unroll
    for (int i = 0; i < 4; ++i)
        #pragma unroll
        for (int j = 0; j < 4; ++j) acc[i][j] = {0.f, 0.f, 0.f, 0.f};

    const int abase = (wr * 64 + l15) * SR + lg * 8;
    const int bbase = (wc * 64 + l15) * SR + lg * 8;

    // ---- prologue: stage tile 0 into buf 0 ----
    {
        #pragma unroll
        for (int it = 0; it < 4; ++it) {
            const int f = it * 512 + tid, n = f >> 3, k4 = f & 7;
            float4 x = {0.f, 0.f, 0.f, 0.f};
            if (n < HW) x = *(const float4*)(mi + (size_t)n * CC + k4 * 4);
            u16x4 h = { f2bf(x.x), f2bf(x.y), f2bf(x.z), f2bf(x.w) };
            *(u16x4*)&As[0][n * SR + k4 * 4] = h;
        }
        #pragma unroll
        for (int it = 0; it < 2; ++it) {
            const int f = it * 512 + tid, ml = f & 127, c4 = f >> 7;
            const int m = mB0 + ml;
            float x0 = 0.f, x1 = 0.f, x2 = 0.f, x3 = 0.f;
            if (m < HW) {
                x0 = qi[(size_t)(c4 * 4 + 0) * HW + m];
                x1 = qi[(size_t)(c4 * 4 + 1) * HW + m];
                x2 = qi[(size_t)(c4 * 4 + 2) * HW + m];
                x3 = qi[(size_t)(c4 * 4 + 3) * HW + m];
            }
            u16x4 h = { f2bf(x0), f2bf(x1), f2bf(x2), f2bf(x3) };
            *(u16x4*)&Bs[0][ml * SR + c4 * 4] = h;
        }
    }
    __syncthreads();

    int cur = 0;
    for (int t = 0; t < CC / KC; ++t) {
        const bool pf = (t < CC / KC - 1);
        const int c0n = (t + 1) * KC;
        float4 pa[4];
        float  pb[8];
        if (pf) {   // issue next-tile global loads BEFORE compute
            #pragma unroll
            for (int it = 0; it < 4; ++it) {
                const int f = it * 512 + tid, n = f >> 3, k4 = f & 7;
                pa[it] = {0.f, 0.f, 0.f, 0.f};
                if (n < HW) pa[it] = *(const float4*)(mi + (size_t)n * CC + c0n + k4 * 4);
            }
            #pragma unroll
            for (int it = 0; it < 2; ++it) {
                const int f = it * 512 + tid, ml = f & 127, c4 = f >> 7;
                const int m = mB0 + ml, c = c0n + c4 * 4;
                #pragma unroll
                for (int jj = 0; jj < 4; ++jj)
                    pb[it * 4 + jj] = (m < HW) ? qi[(size_t)(c + jj) * HW + m] : 0.f;
            }
        }
        // ---- compute on buf[cur] ----
        s16x8 a[4];
        #pragma unroll
        for (int fr = 0; fr < 4; ++fr)
            a[fr] = *(const s16x8*)&As[cur][abase + fr * 16 * SR];
        #pragma unroll
        for (int fc = 0; fc < 4; ++fc) {
            const s16x8 bq = *(const s16x8*)&Bs[cur][bbase + fc * 16 * SR];
            #pragma unroll
            for (int fr = 0; fr < 4; ++fr)
                acc[fr][fc] = __builtin_amdgcn_mfma_f32_16x16x32_bf16(
                    a[fr], bq, acc[fr][fc], 0, 0, 0);
        }
        // ---- convert + write next tile into buf[cur^1] ----
        if (pf) {
            #pragma unroll
            for (int it = 0; it < 4; ++it) {
                const int f = it * 512 + tid, n = f >> 3, k4 = f & 7;
                u16x4 h = { f2bf(pa[it].x), f2bf(pa[it].y), f2bf(pa[it].z), f2bf(pa[it].w) };
                *(u16x4*)&As[cur ^ 1][n * SR + k4 * 4] = h;
            }
            #pragma unroll
            for (int it = 0; it < 2; ++it) {
                const int f = it * 512 + tid, ml = f & 127, c4 = f >> 7;
                u16x4 h = { f2bf(pb[it * 4 + 0]), f2bf(pb[it * 4 + 1]),
                            f2bf(pb[it * 4 + 2]), f2bf(pb[it * 4 + 3]) };
                *(u16x4*)&Bs[cur ^ 1][ml * SR + c4 * 4] = h;
            }
        }
        __syncthreads();
        cur ^= 1;
    }

    // ---- scale + decay mask; column softmax over n ----
    float mx[4];
    #pragma unroll
    for (int fc = 0; fc < 4; ++fc) {
        const int m   = mB0 + wc * 64 + fc * 16 + l15;   // >=225 pad col: benign
        const int mgx = m / 15, mgy = m % 15;
        float cmx = -3.0e38f;
        #pragma unroll
        for (int fr = 0; fr < 4; ++fr)
            #pragma unroll
            for (int r = 0; r < 4; ++r) {
                const int n = wr * 64 + fr * 16 + lg * 4 + r;
                float s;
                if (n < HW) {
                    int dx = n / 15 - mgx; dx = dx < 0 ? -dx : dx;
                    int dy = n % 15 - mgy; dy = dy < 0 ? -dy : dy;
                    s = acc[fr][fc][r] * 0.0625f * exp2f((float)(dx + dy) * L2DECAY);
                } else s = -3.0e38f;
                acc[fr][fc][r] = s;
                cmx = fmaxf(cmx, s);
            }
        cmx = fmaxf(cmx, __shfl_xor(cmx, 16));
        cmx = fmaxf(cmx, __shfl_xor(cmx, 32));
        mx[fc] = cmx;
    }
    if (lane < 16) {
        #pragma unroll
        for (int fc = 0; fc < 4; ++fc) red[wr][wc * 64 + fc * 16 + lane] = mx[fc];
    }
    __syncthreads();
    #pragma unroll
    for (int fc = 0; fc < 4; ++fc) {
        const int col = wc * 64 + fc * 16 + l15;
        mx[fc] = fmaxf(fmaxf(red[0][col], red[1][col]), fmaxf(red[2][col], red[3][col]));
    }
    __syncthreads();   // before reusing red for sums
    float sm[4];
    #pragma unroll
    for (int fc = 0; fc < 4; ++fc) {
        float s = 0.f;
        #pragma unroll
        for (int fr = 0; fr < 4; ++fr)
            #pragma unroll
            for (int r = 0; r < 4; ++r) {
                const float e = exp2f((acc[fr][fc][r] - mx[fc]) * L2E);
                acc[fr][fc][r] = e;
                s += e;
            }
        s += __shfl_xor(s, 16);
        s += __shfl_xor(s, 32);
        sm[fc] = s;
    }
    if (lane < 16) {
        #pragma unroll
        for (int fc = 0; fc < 4; ++fc) red[wr][wc * 64 + fc * 16 + lane] = sm[fc];
    }
    __syncthreads();
    float* pout = out + P_BASE + (size_t)b * P_PER_B;
    #pragma unroll
    for (int fc = 0; fc < 4; ++fc) {
        const int col = wc * 64 + fc * 16 + l15;
        const float inv = 1.f / (red[0][col] + red[1][col] + red[2][col] + red[3][col]);
        const int m = mB0 + wc * 64 + fc * 16 + l15;
        if (m < HW) {
            #pragma unroll
            for (int fr = 0; fr < 4; ++fr)
                #pragma unroll
                for (int r = 0; r < 4; ++r) {
                    const int n = wr * 64 + fr * 16 + lg * 4 + r;
                    if (n < HW) pout[(size_t)n * HW + m] = acc[fr][fc][r] * inv;
                }
        }
    }
}

// ---------------------------------------------------------------------------
// k2: mem[v,m] = sum_n m_out[n,v] * p[n,m].  grid 1024, dbuf K=32 (n-chunks).
// ---------------------------------------------------------------------------
__global__ __launch_bounds__(512, 2) void k2_mfma(
    const float* __restrict__ m_out, float* __restrict__ out)
{
    __shared__ u16 As[2][256 * SR];   // m_out^T rows (v), k=n contig
    __shared__ u16 Bs[2][128 * SR];   // p^T rows (m), k=n contig

    int b, half;  decode_bid((int)blockIdx.x, b, half);
    const int mB0  = half * 128;
    const int tid  = threadIdx.x, lane = tid & 63, wid = tid >> 6;
    const int vr   = wid & 3, wc = wid >> 2;
    const int l15  = lane & 15, lg = lane >> 4;

    const float* mo = m_out + (size_t)b * HW * CC;
    const float* pg = out + P_BASE + (size_t)b * P_PER_B;

    f32x4 acc[4][4];
    #pragma unroll
    for (int i = 0; i < 4; ++i)
        #pragma unroll
        for (int j = 0; j < 4; ++j) acc[i][j] = {0.f, 0.f, 0.f, 0.f};

    const int abase = (vr * 64 + l15) * SR + lg * 8;
    const int bbase = (wc * 64 + l15) * SR + lg * 8;

    // ---- prologue: stage n-tile 0 ----
    {
        #pragma unroll
        for (int it = 0; it < 4; ++it) {
            const int f = it * 512 + tid, v = f & 255, n4 = f >> 8;
            float x[4];
            #pragma unroll
            for (int jj = 0; jj < 4; ++jj) {
                const int n = n4 * 4 + jj;
                x[jj] = (n < HW) ? mo[(size_t)n * CC + v] : 0.f;
            }
            u16x4 h = { f2bf(x[0]), f2bf(x[1]), f2bf(x[2]), f2bf(x[3]) };
            *(u16x4*)&As[0][v * SR + n4 * 4] = h;
        }
        #pragma unroll
        for (int it = 0; it < 2; ++it) {
            const int f = it * 512 + tid, ml = f & 127, n4 = f >> 7;
            const int m = mB0 + ml;
            float x[4];
            #pragma unroll
            for (int jj = 0; jj < 4; ++jj) {
                const int n = n4 * 4 + jj;
                x[jj] = (m < HW && n < HW) ? pg[(size_t)n * HW + m] : 0.f;
            }
            u16x4 h = { f2bf(x[0]), f2bf(x[1]), f2bf(x[2]), f2bf(x[3]) };
            *(u16x4*)&Bs[0][ml * SR + n4 * 4] = h;
        }
    }
    __syncthreads();

    int cur = 0;
    for (int t = 0; t < 8; ++t) {
        const bool pf = (t < 7);
        const int n0n = (t + 1) * KC;
        float pa[16], pb[8];
        if (pf) {
            #pragma unroll
            for (int it = 0; it < 4; ++it) {
                const int f = it * 512 + tid, v = f & 255, n4 = f >> 8;
                #pragma unroll
                for (int jj = 0; jj < 4; ++jj) {
                    const int n = n0n + n4 * 4 + jj;
                    pa[it * 4 + jj] = (n < HW) ? mo[(size_t)n * CC + v] : 0.f;
                }
            }
            #pragma unroll
            for (int it = 0; it < 2; ++it) {
                const int f = it * 512 + tid, ml = f & 127, n4 = f >> 7;
                const int m = mB0 + ml;
                #pragma unroll
                for (int jj = 0; jj < 4; ++jj) {
                    const int n = n0n + n4 * 4 + jj;
                    pb[it * 4 + jj] = (m < HW && n < HW) ? pg[(size_t)n * HW + m] : 0.f;
                }
            }
        }
        // ---- compute on buf[cur] ----
        s16x8 a[4];
        #pragma unroll
        for (int fr = 0; fr < 4; ++fr)
            a[fr] = *(const s16x8*)&As[cur][abase + fr * 16 * SR];
        #pragma unroll
        for (int fc = 0; fc < 4; ++fc) {
            const s16x8 bq = *(const s16x8*)&Bs[cur][bbase + fc * 16 * SR];
            #pragma unroll
            for (int fr = 0; fr < 4; ++fr)
                acc[fr][fc] = __builtin_amdgcn_mfma_f32_16x16x32_bf16(
                    a[fr], bq, acc[fr][fc], 0, 0, 0);
        }
        // ---- write next tile ----
        if (pf) {
            #pragma unroll
            for (int it = 0; it < 4; ++it) {
                const int f = it * 512 + tid, v = f & 255, n4 = f >> 8;
                u16x4 h = { f2bf(pa[it * 4 + 0]), f2bf(pa[it * 4 + 1]),
                            f2bf(pa[it * 4 + 2]), f2bf(pa[it * 4 + 3]) };
                *(u16x4*)&As[cur ^ 1][v * SR + n4 * 4] = h;
            }
            #pragma unroll
            for (int it = 0; it < 2; ++it) {
                const int f = it * 512 + tid, ml = f & 127, n4 = f >> 7;
                u16x4 h = { f2bf(pb[it * 4 + 0]), f2bf(pb[it * 4 + 1]),
                            f2bf(pb[it * 4 + 2]), f2bf(pb[it * 4 + 3]) };
                *(u16x4*)&Bs[cur ^ 1][ml * SR + n4 * 4] = h;
            }
        }
        __syncthreads();
        cur ^= 1;
    }

    float* ob = out + (size_t)b * MEMOUT_PER_B;
    #pragma unroll
    for (int fc = 0; fc < 4; ++fc) {
        const int m = mB0 + wc * 64 + fc * 16 + l15;
        if (m < HW) {
            #pragma unroll
            for (int fr = 0; fr < 4; ++fr)
                #pragma unroll
                for (int r = 0; r < 4; ++r) {
                    const int v = vr * 64 + fr * 16 + lg * 4 + r;
                    ob[(size_t)v * HW + m] = acc[fr][fc][r];
                }
        }
    }
}

// ---------------------------------------------------------------------------
// k3: copy q_out into second channel half of mem_out (float4 coalesced)
// ---------------------------------------------------------------------------
__global__ __launch_bounds__(256) void k3_copy(
    const float4* __restrict__ q_out, float4* __restrict__ out)
{
    const size_t g = (size_t)blockIdx.x * 256 + threadIdx.x;  // < 512*14400
    const size_t b = g / 14400;
    const size_t r = g - b * 14400;
    out[b * 28800 + 14400 + r] = q_out[b * 14400 + r];
}

extern "C" void kernel_launch(void* const* d_in, const int* in_sizes, int n_in,
                              void* d_out, int out_size, void* d_ws, size_t ws_size,
                              hipStream_t stream) {
    const float* m_in  = (const float*)d_in[0];
    const float* m_out = (const float*)d_in[1];
    const float* q_in  = (const float*)d_in[2];
    const float* q_out = (const float*)d_in[3];
    float* out = (float*)d_out;

    k1_mfma<<<1024, 512, 0, stream>>>(m_in, q_in, out);
    k2_mfma<<<1024, 512, 0, stream>>>(m_out, out);
    k3_copy<<<(512 * 14400) / 256, 256, 0, stream>>>((const float4*)q_out, (float4*)out);
}